// Round 13
// baseline (266.036 us; speedup 1.0000x reference)
//
#include <hip/hip_runtime.h>
#include <hip/hip_bf16.h>
#include <hip/hip_fp16.h>

#define Bc 8
#define Nc 256
#define Dc 256
#define Hc 16
#define DKc 16
#define MSc 16
#define FFc 512
#define SZc 524288          // B*N*D elements
#define WHALF 524288        // bf16 elems of one half's 6 transposed weights
#define FFH 1048576         // B*N*FF elements

typedef __hip_bfloat16 bf16;
typedef __attribute__((ext_vector_type(8))) short bfrag8;   // 8 bf16 (4 VGPR)
typedef __attribute__((ext_vector_type(4))) float f32x4;    // MFMA acc

__device__ __forceinline__ short f2bs(float x) {
    bf16 t = __float2bfloat16(x);
    return *reinterpret_cast<short*>(&t);
}

// ROCm 7.2 lacks __hmax2 for __half2 (only bf16 overload); emit the packed
// max directly (VOP3P, gfx950).
__device__ __forceinline__ __half2 pkmax2(__half2 a, __half2 b) {
    __half2 d;
    asm volatile("v_pk_max_f16 %0, %1, %2" : "=v"(d) : "v"(a), "v"(b));
    return d;
}

// ---------------------------------------------------------------------------
// Dispatch 1: setup. grid (256, 15), block 256.
//  y=0/1: emb fp32->bf16; y=2: zero stats; y=3..14: weight transpose->bf16
// ---------------------------------------------------------------------------
__global__ void setup_kernel(const float* __restrict__ e0, const float* __restrict__ e1,
                             bf16* __restrict__ o0, bf16* __restrict__ o1,
                             float* __restrict__ statsB,
                             const float* rWq, const float* rWk, const float* rWv,
                             const float* rcw, const float* rw1, const float* rw2,
                             const float* cWq, const float* cWk, const float* cWv,
                             const float* ccw, const float* cw1, const float* cw2,
                             bf16* __restrict__ WT) {
    int y = blockIdx.y;
    if (y < 2) {
        const float* src = y ? e1 : e0;
        bf16* dst = y ? o1 : o0;
        size_t base = (size_t)blockIdx.x * 2048 + threadIdx.x;
#pragma unroll
        for (int i = 0; i < 8; ++i)
            dst[base + i * 256] = __float2bfloat16(src[base + i * 256]);
        return;
    }
    if (y == 2) {
        if (blockIdx.x < 64) statsB[blockIdx.x * 256 + threadIdx.x] = 0.f;
        return;
    }
    int z = y - 3;                    // 0..11
    int p = z / 6, widx = z % 6;
    const float* src; int K, N; size_t off;
    switch (widx) {
        case 0: src = p ? cWq : rWq; K = 256; N = 256; off = 0; break;
        case 1: src = p ? cWk : rWk; K = 256; N = 256; off = 65536; break;
        case 2: src = p ? cWv : rWv; K = 256; N = 256; off = 131072; break;
        case 3: src = p ? ccw : rcw; K = 256; N = 256; off = 196608; break;
        case 4: src = p ? cw1 : rw1; K = 256; N = 512; off = 262144; break;
        default: src = p ? cw2 : rw2; K = 512; N = 256; off = 393216; break;
    }
    int Ntiles = N >> 5, Ktiles = K >> 5;
    if ((int)blockIdx.x >= Ktiles * Ntiles) return;
    int kt = blockIdx.x / Ntiles, nt = blockIdx.x - kt * Ntiles;
    int k0 = kt * 32, n0 = nt * 32;
    bf16* dst = WT + (size_t)p * WHALF + off;
    __shared__ float t[32][33];
    int tx = threadIdx.x & 31, ty = threadIdx.x >> 5;   // 32 x 8
#pragma unroll
    for (int i = 0; i < 4; ++i)
        t[ty + i * 8][tx] = src[(size_t)(k0 + ty + i * 8) * N + n0 + tx];
    __syncthreads();
#pragma unroll
    for (int i = 0; i < 4; ++i)
        dst[(size_t)(n0 + ty + i * 8) * K + k0 + tx] = __float2bfloat16(t[tx][ty + i * 8]);
}

__device__ __forceinline__ void mfma_loop(const short* pa0, const short* pa1,
                                          const short* pb, int K,
                                          f32x4& acc0, f32x4& acc1) {
    for (int kt = 0; kt < K; kt += 32) {
        bfrag8 a0 = *(const bfrag8*)(pa0 + kt);
        bfrag8 a1 = *(const bfrag8*)(pa1 + kt);
        bfrag8 b  = *(const bfrag8*)(pb + kt);
        acc0 = __builtin_amdgcn_mfma_f32_16x16x32_bf16(a0, b, acc0, 0, 0, 0);
        acc1 = __builtin_amdgcn_mfma_f32_16x16x32_bf16(a1, b, acc1, 0, 0, 0);
    }
}

// ---------------------------------------------------------------------------
// Dispatch 2: QKV both halves. z = p*3 + j. Head-major fp32 out.
// ---------------------------------------------------------------------------
__global__ void gemm_qkv_kernel(const short* __restrict__ embRb, const short* __restrict__ embCb,
                                const short* __restrict__ WT, float* __restrict__ qkv) {
    int z = blockIdx.z;
    int p = z / 3, j = z % 3;
    const short* A  = (j == 0) ? (p ? embCb : embRb) : (p ? embRb : embCb);
    const short* BT = WT + (size_t)p * WHALF + j * 65536;
    float* out = qkv + (size_t)z * SZc;

    int lane = threadIdx.x & 63, w = threadIdx.x >> 6;
    int m_base = blockIdx.x * 64 + (w & 1) * 32;
    int n_base = blockIdx.y * 32 + (w >> 1) * 16;
    int mr = lane & 15, quad = lane >> 4;

    const short* pa0 = A + (size_t)(m_base + mr) * 256 + quad * 8;
    const short* pa1 = pa0 + 16 * 256;
    const short* pb  = BT + (size_t)(n_base + mr) * 256 + quad * 8;

    f32x4 acc0 = {0.f, 0.f, 0.f, 0.f}, acc1 = {0.f, 0.f, 0.f, 0.f};
    mfma_loop(pa0, pa1, pb, 256, acc0, acc1);

    int col = n_base + mr;
    int h = col >> 4, dk = col & 15;
#pragma unroll
    for (int r = 0; r < 4; ++r) {
        int row0 = m_base + quad * 4 + r;
        int row1 = row0 + 16;
        int b0 = row0 >> 8, n0 = row0 & 255;
        int b1 = row1 >> 8, n1 = row1 & 255;
        out[((size_t)(b0 * Hc + h) * Nc + n0) * DKc + dk] = acc0[r];
        out[((size_t)(b1 * Hc + h) * Nc + n1) * DKc + dk] = acc1[r];
    }
}

// ---------------------------------------------------------------------------
// Dispatch 3: fused attention, both halves. grid (B, H, 32).
// Phase-1 MLP in packed fp16 (hfma2 + v_pk_max_f16): 64 -> ~26 ops/entry.
// sPart stride-72 quad offset: bank offsets {0,8,16,24} -> 2 lanes/bank (free).
// ---------------------------------------------------------------------------
__global__ void attn_kernel(const float* __restrict__ qkv, const float* __restrict__ cost,
                            const float* rm1w, const float* rm1b,
                            const float* rm2w, const float* rm2b,
                            const float* cm1w, const float* cm1b,
                            const float* cm2w, const float* cm2b,
                            bf16* __restrict__ attnb) {
    int b = blockIdx.x, h = blockIdx.y;
    int p = blockIdx.z >> 4, rc = blockIdx.z & 15;
    int tr = p;
    const float* Q = qkv + (size_t)(p * 3 + 0) * SZc;
    const float* K = qkv + (size_t)(p * 3 + 1) * SZc;
    const float* V = qkv + (size_t)(p * 3 + 2) * SZc;
    const float* m1w = p ? cm1w : rm1w;
    const float* m1b = p ? cm1b : rm1b;
    const float* m2w = p ? cm2w : rm2w;
    const float* m2b = p ? cm2b : rm2b;
    bf16* out_concat = attnb + (size_t)p * SZc;

    int bh = b * Hc + h;
    int r0 = rc * 16;
    int c = threadIdx.x;
    int lane = c & 63, wid = c >> 6;

    __shared__ __align__(16) short sVT[16 * 264];
    __shared__ __align__(16) short sEb[16 * 264];
    __shared__ float sQ[16][16];
    __shared__ float sPart[4 * 280];   // [wid][quad*72 + r*16 + mr]
    __shared__ float sSum[16 * 4];
    __shared__ float sm1w[32], sm1b[16], sm2w[16], sm2bS[1];

    float kreg[16];
    {
        const float* kp = K + ((size_t)bh * Nc + c) * DKc;
        const float* vp = V + ((size_t)bh * Nc + c) * DKc;
#pragma unroll
        for (int i = 0; i < 4; ++i) {
            float4 kv = *(const float4*)(kp + i * 4);
            float4 vv = *(const float4*)(vp + i * 4);
            kreg[i * 4]     = kv.x; kreg[i * 4 + 1] = kv.y;
            kreg[i * 4 + 2] = kv.z; kreg[i * 4 + 3] = kv.w;
            sVT[(i * 4 + 0) * 264 + c] = f2bs(vv.x);
            sVT[(i * 4 + 1) * 264 + c] = f2bs(vv.y);
            sVT[(i * 4 + 2) * 264 + c] = f2bs(vv.z);
            sVT[(i * 4 + 3) * 264 + c] = f2bs(vv.w);
        }
    }
    if (c < 64) {
        float4 qv = *(const float4*)(Q + ((size_t)bh * Nc + r0) * DKc + c * 4);
        int rl = c >> 2, off = (c & 3) * 4;
        sQ[rl][off] = qv.x; sQ[rl][off + 1] = qv.y;
        sQ[rl][off + 2] = qv.z; sQ[rl][off + 3] = qv.w;
    } else if (c < 96)   sm1w[c - 64]  = m1w[h * 32 + (c - 64)];
    else if (c < 112)    sm1b[c - 96]  = m1b[h * 16 + (c - 96)];
    else if (c < 128)    sm2w[c - 112] = m2w[h * 16 + (c - 112)];
    else if (c == 128)   sm2bS[0] = m2b[h];
    __syncthreads();

    // pack MLP coefficients into half2 registers (one-time per thread)
    __half2 pa2[8], pb2[8], pc2[8], pw2[8];
#pragma unroll
    for (int m = 0; m < 8; ++m) {
        pa2[m] = __floats2half2_rn(sm1w[2 * m], sm1w[2 * m + 1]);
        pb2[m] = __floats2half2_rn(sm1w[16 + 2 * m], sm1w[16 + 2 * m + 1]);
        pc2[m] = __floats2half2_rn(sm1b[2 * m], sm1b[2 * m + 1]);
        pw2[m] = __floats2half2_rn(sm2w[2 * m], sm2w[2 * m + 1]);
    }
    const __half2 z2 = __floats2half2_rn(0.f, 0.f);
    float m2bias = sm2bS[0];

    const float* costR = cost + (size_t)b * Nc * Nc;
    float creg[16];
    if (tr) {
#pragma unroll
        for (int g = 0; g < 4; ++g) {
            float4 cv = *(const float4*)(costR + (size_t)c * Nc + r0 + g * 4);
            creg[g * 4]     = cv.x; creg[g * 4 + 1] = cv.y;
            creg[g * 4 + 2] = cv.z; creg[g * 4 + 3] = cv.w;
        }
    }

    for (int rl = 0; rl < 16; ++rl) {
        float dot = 0.f;
#pragma unroll
        for (int k = 0; k < 16; ++k) dot += kreg[k] * sQ[rl][k];
        dot *= 0.25f;
        float cost_v = tr ? creg[rl] : costR[(size_t)(r0 + rl) * Nc + c];
        __half2 d2 = __float2half2_rn(dot);
        __half2 cv2 = __float2half2_rn(cost_v);
        __half2 acc2 = z2;
#pragma unroll
        for (int m = 0; m < 8; ++m) {
            __half2 t = __hfma2(d2, pa2[m], __hfma2(cv2, pb2[m], pc2[m]));
            t = pkmax2(t, z2);
            acc2 = __hfma2(t, pw2[m], acc2);
        }
        float mixed = m2bias + __low2float(acc2) + __high2float(acc2);
        float e = __expf(mixed);
        sEb[rl * 264 + c] = f2bs(e);
        float s = e;
#pragma unroll
        for (int off = 32; off > 0; off >>= 1) s += __shfl_xor(s, off);
        if (lane == 0) sSum[rl * 4 + wid] = s;
    }
    __syncthreads();

    {
        int mr = lane & 15, quad = lane >> 4;
        const short* pa = &sEb[mr * 264 + wid * 64 + quad * 8];
        const short* pb = &sVT[mr * 264 + wid * 64 + quad * 8];
        f32x4 acc = {0.f, 0.f, 0.f, 0.f};
        bfrag8 a0 = *(const bfrag8*)pa;
        bfrag8 b0 = *(const bfrag8*)pb;
        acc = __builtin_amdgcn_mfma_f32_16x16x32_bf16(a0, b0, acc, 0, 0, 0);
        bfrag8 a1 = *(const bfrag8*)(pa + 32);
        bfrag8 b1 = *(const bfrag8*)(pb + 32);
        acc = __builtin_amdgcn_mfma_f32_16x16x32_bf16(a1, b1, acc, 0, 0, 0);
        // C layout: row = quad*4+r (m index), col = mr (n index)
#pragma unroll
        for (int r = 0; r < 4; ++r)
            sPart[wid * 280 + quad * 72 + r * 16 + mr] = acc[r];
    }
    __syncthreads();

    {
        int r = c >> 4, dk = c & 15;
        int quad = r >> 2, rr = r & 3;
        int idx = quad * 72 + rr * 16 + dk;
        float o = sPart[idx] + sPart[280 + idx] + sPart[560 + idx] + sPart[840 + idx];
        float sum = sSum[r * 4] + sSum[r * 4 + 1] + sSum[r * 4 + 2] + sSum[r * 4 + 3];
        out_concat[((size_t)(b * Nc + r0 + r)) * Dc + h * DKc + dk] =
            __float2bfloat16(o / sum);
    }
}

// ---------------------------------------------------------------------------
// Dispatch 4: concat GEMM + bias + residual + stats1 atomics. grid (32,8,2).
// ---------------------------------------------------------------------------
__global__ void gemm_cat_kernel(const short* __restrict__ attnb, const short* __restrict__ WT,
                                const float* rcb, const float* ccb,
                                const float* __restrict__ resR, const float* __restrict__ resC,
                                float* __restrict__ x1, float* __restrict__ stats1) {
    int p = blockIdx.z;
    const short* A  = attnb + (size_t)p * SZc;
    const short* BT = WT + (size_t)p * WHALF + 196608;
    const float* bias = p ? ccb : rcb;
    const float* res  = p ? resC : resR;
    float* outF = x1 + (size_t)p * SZc;
    float* st   = stats1 + p * 4096;

    int lane = threadIdx.x & 63, w = threadIdx.x >> 6;
    int m_base = blockIdx.x * 64 + (w & 1) * 32;
    int n_base = blockIdx.y * 32 + (w >> 1) * 16;
    int mr = lane & 15, quad = lane >> 4;

    const short* pa0 = A + (size_t)(m_base + mr) * 256 + quad * 8;
    const short* pa1 = pa0 + (size_t)16 * 256;
    const short* pb  = BT + (size_t)(n_base + mr) * 256 + quad * 8;

    f32x4 acc0 = {0.f, 0.f, 0.f, 0.f}, acc1 = {0.f, 0.f, 0.f, 0.f};
    mfma_loop(pa0, pa1, pb, 256, acc0, acc1);

    int col = n_base + mr;
    float bv = bias[col];
    int bb = m_base >> 8;
    float ssum = 0.f, ssq = 0.f;
#pragma unroll
    for (int r = 0; r < 4; ++r) {
        int row0 = m_base + quad * 4 + r;
        int row1 = row0 + 16;
        float v0 = acc0[r] + bv + res[(size_t)row0 * 256 + col];
        float v1 = acc1[r] + bv + res[(size_t)row1 * 256 + col];
        outF[(size_t)row0 * 256 + col] = v0;
        outF[(size_t)row1 * 256 + col] = v1;
        ssum += v0 + v1;
        ssq  += v0 * v0 + v1 * v1;
    }
    atomicAdd(&st[(bb * 256 + col) * 2],     ssum);
    atomicAdd(&st[(bb * 256 + col) * 2 + 1], ssq);
}

// ---------------------------------------------------------------------------
// Dispatch 5: FF1 with on-the-fly norm1 of A. grid (32,16,2).
// ---------------------------------------------------------------------------
__global__ __launch_bounds__(256) void gemm_ff1n_kernel(
        const float* __restrict__ x1, const float* __restrict__ stats1,
        const float* rn1s, const float* rn1b, const float* cn1s, const float* cn1b,
        const short* __restrict__ WT, const float* rb1, const float* cb1,
        bf16* __restrict__ ffh) {
    int p = blockIdx.z;
    const float* X   = x1 + (size_t)p * SZc;
    const float* st  = stats1 + p * 4096;
    const float* n1s = p ? cn1s : rn1s;
    const float* n1b = p ? cn1b : rn1b;
    const short* BT  = WT + (size_t)p * WHALF + 262144;
    const float* bias = p ? cb1 : rb1;
    bf16* outB = ffh + (size_t)p * FFH;

    __shared__ __align__(16) short sA[64 * 264];
    int c = threadIdx.x;
    int m_base = blockIdx.x * 64;
    int b = m_base >> 8;

    float s = st[(b * 256 + c) * 2];
    float q = st[(b * 256 + c) * 2 + 1];
    float mean = s * (1.f / Nc);
    float var = q * (1.f / Nc) - mean * mean;
    float inv = rsqrtf(var + 1e-5f) * n1s[c];
    float nb = n1b[c];
#pragma unroll 8
    for (int i = 0; i < 64; ++i) {
        float v = X[(size_t)(m_base + i) * 256 + c];
        sA[i * 264 + c] = f2bs((v - mean) * inv + nb);
    }
    __syncthreads();

    int lane = c & 63, w = c >> 6;
    int mloc = (w & 1) * 32;
    int n_base = blockIdx.y * 32 + (w >> 1) * 16;
    int mr = lane & 15, quad = lane >> 4;

    const short* pa0 = &sA[(mloc + mr) * 264 + quad * 8];
    const short* pa1 = pa0 + 16 * 264;
    const short* pb  = BT + (size_t)(n_base + mr) * 256 + quad * 8;

    f32x4 acc0 = {0.f, 0.f, 0.f, 0.f}, acc1 = {0.f, 0.f, 0.f, 0.f};
#pragma unroll
    for (int kt = 0; kt < 256; kt += 32) {
        bfrag8 a0 = *(const bfrag8*)(pa0 + kt);
        bfrag8 a1 = *(const bfrag8*)(pa1 + kt);
        bfrag8 bb = *(const bfrag8*)(pb + kt);
        acc0 = __builtin_amdgcn_mfma_f32_16x16x32_bf16(a0, bb, acc0, 0, 0, 0);
        acc1 = __builtin_amdgcn_mfma_f32_16x16x32_bf16(a1, bb, acc1, 0, 0, 0);
    }

    int col = n_base + mr;
    float bv = bias[col];
#pragma unroll
    for (int r = 0; r < 4; ++r) {
        int row0 = m_base + mloc + quad * 4 + r;
        int row1 = row0 + 16;
        outB[(size_t)row0 * 512 + col] = __float2bfloat16(fmaxf(acc0[r] + bv, 0.f));
        outB[(size_t)row1 * 512 + col] = __float2bfloat16(fmaxf(acc1[r] + bv, 0.f));
    }
}

// ---------------------------------------------------------------------------
// Dispatch 6: FF2 + recomputed norm1 residual + stats2 atomics. grid (32,8,2).
// ---------------------------------------------------------------------------
__global__ void gemm_ff2n_kernel(const short* __restrict__ ffh, const short* __restrict__ WT,
                                 const float* rb2, const float* cb2,
                                 const float* __restrict__ x1, const float* __restrict__ stats1,
                                 const float* rn1s, const float* rn1b,
                                 const float* cn1s, const float* cn1b,
                                 float* __restrict__ ff2, float* __restrict__ stats2) {
    int p = blockIdx.z;
    const short* A  = ffh + (size_t)p * FFH;
    const short* BT = WT + (size_t)p * WHALF + 393216;
    const float* bias = p ? cb2 : rb2;
    const float* X   = x1 + (size_t)p * SZc;
    const float* st1 = stats1 + p * 4096;
    const float* n1s = p ? cn1s : rn1s;
    const float* n1b = p ? cn1b : rn1b;
    float* outF = ff2 + (size_t)p * SZc;
    float* st2  = stats2 + p * 4096;

    int lane = threadIdx.x & 63, w = threadIdx.x >> 6;
    int m_base = blockIdx.x * 64 + (w & 1) * 32;
    int n_base = blockIdx.y * 32 + (w >> 1) * 16;
    int mr = lane & 15, quad = lane >> 4;

    const short* pa0 = A + (size_t)(m_base + mr) * 512 + quad * 8;
    const short* pa1 = pa0 + (size_t)16 * 512;
    const short* pb  = BT + (size_t)(n_base + mr) * 512 + quad * 8;

    f32x4 acc0 = {0.f, 0.f, 0.f, 0.f}, acc1 = {0.f, 0.f, 0.f, 0.f};
    mfma_loop(pa0, pa1, pb, 512, acc0, acc1);

    int col = n_base + mr;
    int bb = m_base >> 8;
    float s1 = st1[(bb * 256 + col) * 2];
    float q1 = st1[(bb * 256 + col) * 2 + 1];
    float mean1 = s1 * (1.f / Nc);
    float var1 = q1 * (1.f / Nc) - mean1 * mean1;
    float inv1 = rsqrtf(var1 + 1e-5f) * n1s[col];
    float nb1 = n1b[col];
    float bv = bias[col];

    float ssum = 0.f, ssq = 0.f;
#pragma unroll
    for (int r = 0; r < 4; ++r) {
        int row0 = m_base + quad * 4 + r;
        int row1 = row0 + 16;
        float res0 = (X[(size_t)row0 * 256 + col] - mean1) * inv1 + nb1;
        float res1 = (X[(size_t)row1 * 256 + col] - mean1) * inv1 + nb1;
        float v0 = acc0[r] + bv + res0;
        float v1 = acc1[r] + bv + res1;
        outF[(size_t)row0 * 256 + col] = v0;
        outF[(size_t)row1 * 256 + col] = v1;
        ssum += v0 + v1;
        ssq  += v0 * v0 + v1 * v1;
    }
    atomicAdd(&st2[(bb * 256 + col) * 2],     ssum);
    atomicAdd(&st2[(bb * 256 + col) * 2 + 1], ssq);
}

// ---------------------------------------------------------------------------
// Dispatch 7: final norm2 apply -> output. grid (2048, 2).
// ---------------------------------------------------------------------------
__global__ void apply_kernel(const float* __restrict__ x, const float* __restrict__ stats,
                             const float* sR, const float* bR,
                             const float* sC, const float* bC,
                             float* __restrict__ outF) {
    int p = blockIdx.y;
    int row = blockIdx.x;
    int b = row >> 8;
    int d = threadIdx.x;
    const float* st = stats + p * 4096;
    float sum = st[(b * 256 + d) * 2];
    float sq  = st[(b * 256 + d) * 2 + 1];
    float mean = sum * (1.f / Nc);
    float var = sq * (1.f / Nc) - mean * mean;
    float inv = rsqrtf(var + 1e-5f);
    float scale = (p ? sC : sR)[d];
    float bias  = (p ? bC : bR)[d];
    float v = x[(size_t)p * SZc + (size_t)row * Dc + d];
    outF[(size_t)p * SZc + (size_t)row * Dc + d] = (v - mean) * inv * scale + bias;
}

extern "C" void kernel_launch(void* const* d_in, const int* in_sizes, int n_in,
                              void* d_out, int out_size, void* d_ws, size_t ws_size,
                              hipStream_t stream) {
    const float* row_emb = (const float*)d_in[0];
    const float* col_emb = (const float*)d_in[1];
    const float* cost    = (const float*)d_in[2];
    float* out = (float*)d_out;
    float* ws = (float*)d_ws;
    // per-half param index: 0 Wq, 1 Wk, 2 Wv, 3 m1w, 4 m1b, 5 m2w, 6 m2b,
    // 7 cw, 8 cb, 9 n1s, 10 n1b, 11 w1, 12 b1, 13 w2, 14 b2, 15 n2s, 16 n2b
#define RP(i) ((const float*)d_in[3 + (i)])
#define CP(i) ((const float*)d_in[20 + (i)])

    float* qkv    = ws;                            // 6 SZ
    float* x1     = ws + 6 * (size_t)SZc;          // 2 SZ
    float* ff2    = ws + 8 * (size_t)SZc;          // 2 SZ
    float* statsB = ws + 10 * (size_t)SZc;         // 16384
    bf16* bfbase  = (bf16*)(statsB + 16384);
    bf16* embRb = bfbase;                          // SZ
    bf16* embCb = embRb + SZc;                     // SZ
    bf16* attnb = embCb + SZc;                     // 2 SZ
    bf16* ffh   = attnb + 2 * (size_t)SZc;         // 4 SZ
    bf16* WT    = ffh + 4 * (size_t)SZc;           // 2 SZ
    float* stats1 = statsB;
    float* stats2 = statsB + 8192;

    setup_kernel<<<dim3(256, 15), 256, 0, stream>>>(
        row_emb, col_emb, embRb, embCb, statsB,
        RP(0), RP(1), RP(2), RP(7), RP(11), RP(13),
        CP(0), CP(1), CP(2), CP(7), CP(11), CP(13), WT);
    gemm_qkv_kernel<<<dim3(32, 8, 6), 256, 0, stream>>>(
        (const short*)embRb, (const short*)embCb, (const short*)WT, qkv);
    attn_kernel<<<dim3(Bc, Hc, 32), 256, 0, stream>>>(
        qkv, cost, RP(3), RP(4), RP(5), RP(6), CP(3), CP(4), CP(5), CP(6), attnb);
    gemm_cat_kernel<<<dim3(32, 8, 2), 256, 0, stream>>>(
        (const short*)attnb, (const short*)WT, RP(8), CP(8), row_emb, col_emb, x1, stats1);
    gemm_ff1n_kernel<<<dim3(32, 16, 2), 256, 0, stream>>>(
        x1, stats1, RP(9), RP(10), CP(9), CP(10),
        (const short*)WT, RP(12), CP(12), ffh);
    gemm_ff2n_kernel<<<dim3(32, 8, 2), 256, 0, stream>>>(
        (const short*)ffh, (const short*)WT, RP(14), CP(14),
        x1, stats1, RP(9), RP(10), CP(9), CP(10), ff2, stats2);
    apply_kernel<<<dim3(2048, 2), 256, 0, stream>>>(
        ff2, stats2, RP(15), RP(16), CP(15), CP(16), out);
#undef RP
#undef CP
}

// Round 14
// 246.384 us; speedup vs baseline: 1.0798x; 1.0798x over previous
//
#include <hip/hip_runtime.h>
#include <hip/hip_bf16.h>
#include <hip/hip_fp16.h>

#define Bc 8
#define Nc 256
#define Dc 256
#define Hc 16
#define DKc 16
#define MSc 16
#define FFc 512
#define SZc 524288          // B*N*D elements
#define WHALF 524288        // bf16 elems of one half's 6 transposed weights
#define FFH 1048576         // B*N*FF elements

typedef __hip_bfloat16 bf16;
typedef __attribute__((ext_vector_type(8))) short bfrag8;   // 8 bf16 (4 VGPR)
typedef __attribute__((ext_vector_type(4))) float f32x4;    // MFMA acc
typedef _Float16 h2 __attribute__((ext_vector_type(2)));    // packed fp16 pair

__device__ __forceinline__ short f2bs(float x) {
    bf16 t = __float2bfloat16(x);
    return *reinterpret_cast<short*>(&t);
}

// ---------------------------------------------------------------------------
// Dispatch 1: setup. grid (256, 15), block 256.
//  y=0/1: emb fp32->bf16; y=2: zero stats; y=3..14: weight transpose->bf16
// ---------------------------------------------------------------------------
__global__ void setup_kernel(const float* __restrict__ e0, const float* __restrict__ e1,
                             bf16* __restrict__ o0, bf16* __restrict__ o1,
                             float* __restrict__ statsB,
                             const float* rWq, const float* rWk, const float* rWv,
                             const float* rcw, const float* rw1, const float* rw2,
                             const float* cWq, const float* cWk, const float* cWv,
                             const float* ccw, const float* cw1, const float* cw2,
                             bf16* __restrict__ WT) {
    int y = blockIdx.y;
    if (y < 2) {
        const float* src = y ? e1 : e0;
        bf16* dst = y ? o1 : o0;
        size_t base = (size_t)blockIdx.x * 2048 + threadIdx.x;
#pragma unroll
        for (int i = 0; i < 8; ++i)
            dst[base + i * 256] = __float2bfloat16(src[base + i * 256]);
        return;
    }
    if (y == 2) {
        if (blockIdx.x < 64) statsB[blockIdx.x * 256 + threadIdx.x] = 0.f;
        return;
    }
    int z = y - 3;                    // 0..11
    int p = z / 6, widx = z % 6;
    const float* src; int K, N; size_t off;
    switch (widx) {
        case 0: src = p ? cWq : rWq; K = 256; N = 256; off = 0; break;
        case 1: src = p ? cWk : rWk; K = 256; N = 256; off = 65536; break;
        case 2: src = p ? cWv : rWv; K = 256; N = 256; off = 131072; break;
        case 3: src = p ? ccw : rcw; K = 256; N = 256; off = 196608; break;
        case 4: src = p ? cw1 : rw1; K = 256; N = 512; off = 262144; break;
        default: src = p ? cw2 : rw2; K = 512; N = 256; off = 393216; break;
    }
    int Ntiles = N >> 5, Ktiles = K >> 5;
    if ((int)blockIdx.x >= Ktiles * Ntiles) return;
    int kt = blockIdx.x / Ntiles, nt = blockIdx.x - kt * Ntiles;
    int k0 = kt * 32, n0 = nt * 32;
    bf16* dst = WT + (size_t)p * WHALF + off;
    __shared__ float t[32][33];
    int tx = threadIdx.x & 31, ty = threadIdx.x >> 5;   // 32 x 8
#pragma unroll
    for (int i = 0; i < 4; ++i)
        t[ty + i * 8][tx] = src[(size_t)(k0 + ty + i * 8) * N + n0 + tx];
    __syncthreads();
#pragma unroll
    for (int i = 0; i < 4; ++i)
        dst[(size_t)(n0 + ty + i * 8) * K + k0 + tx] = __float2bfloat16(t[tx][ty + i * 8]);
}

__device__ __forceinline__ void mfma_loop(const short* pa0, const short* pa1,
                                          const short* pb, int K,
                                          f32x4& acc0, f32x4& acc1) {
    for (int kt = 0; kt < K; kt += 32) {
        bfrag8 a0 = *(const bfrag8*)(pa0 + kt);
        bfrag8 a1 = *(const bfrag8*)(pa1 + kt);
        bfrag8 b  = *(const bfrag8*)(pb + kt);
        acc0 = __builtin_amdgcn_mfma_f32_16x16x32_bf16(a0, b, acc0, 0, 0, 0);
        acc1 = __builtin_amdgcn_mfma_f32_16x16x32_bf16(a1, b, acc1, 0, 0, 0);
    }
}

// ---------------------------------------------------------------------------
// Dispatch 2: QKV both halves. z = p*3 + j. Head-major fp32 out.
// ---------------------------------------------------------------------------
__global__ void gemm_qkv_kernel(const short* __restrict__ embRb, const short* __restrict__ embCb,
                                const short* __restrict__ WT, float* __restrict__ qkv) {
    int z = blockIdx.z;
    int p = z / 3, j = z % 3;
    const short* A  = (j == 0) ? (p ? embCb : embRb) : (p ? embRb : embCb);
    const short* BT = WT + (size_t)p * WHALF + j * 65536;
    float* out = qkv + (size_t)z * SZc;

    int lane = threadIdx.x & 63, w = threadIdx.x >> 6;
    int m_base = blockIdx.x * 64 + (w & 1) * 32;
    int n_base = blockIdx.y * 32 + (w >> 1) * 16;
    int mr = lane & 15, quad = lane >> 4;

    const short* pa0 = A + (size_t)(m_base + mr) * 256 + quad * 8;
    const short* pa1 = pa0 + 16 * 256;
    const short* pb  = BT + (size_t)(n_base + mr) * 256 + quad * 8;

    f32x4 acc0 = {0.f, 0.f, 0.f, 0.f}, acc1 = {0.f, 0.f, 0.f, 0.f};
    mfma_loop(pa0, pa1, pb, 256, acc0, acc1);

    int col = n_base + mr;
    int h = col >> 4, dk = col & 15;
#pragma unroll
    for (int r = 0; r < 4; ++r) {
        int row0 = m_base + quad * 4 + r;
        int row1 = row0 + 16;
        int b0 = row0 >> 8, n0 = row0 & 255;
        int b1 = row1 >> 8, n1 = row1 & 255;
        out[((size_t)(b0 * Hc + h) * Nc + n0) * DKc + dk] = acc0[r];
        out[((size_t)(b1 * Hc + h) * Nc + n1) * DKc + dk] = acc1[r];
    }
}

// ---------------------------------------------------------------------------
// Dispatch 3: fused attention, both halves. grid (B, H, 32).
// Phase-1 MLP in packed fp16 via _Float16 vectors (compiler-visible, no asm
// -> no spill; R13's asm version spilled 31MB scratch/dispatch).
// sPart stride-72 quad offset: bank offsets {0,8,16,24} -> 2 lanes/bank (free).
// ---------------------------------------------------------------------------
__global__ void attn_kernel(const float* __restrict__ qkv, const float* __restrict__ cost,
                            const float* rm1w, const float* rm1b,
                            const float* rm2w, const float* rm2b,
                            const float* cm1w, const float* cm1b,
                            const float* cm2w, const float* cm2b,
                            bf16* __restrict__ attnb) {
    int b = blockIdx.x, h = blockIdx.y;
    int p = blockIdx.z >> 4, rc = blockIdx.z & 15;
    int tr = p;
    const float* Q = qkv + (size_t)(p * 3 + 0) * SZc;
    const float* K = qkv + (size_t)(p * 3 + 1) * SZc;
    const float* V = qkv + (size_t)(p * 3 + 2) * SZc;
    const float* m1w = p ? cm1w : rm1w;
    const float* m1b = p ? cm1b : rm1b;
    const float* m2w = p ? cm2w : rm2w;
    const float* m2b = p ? cm2b : rm2b;
    bf16* out_concat = attnb + (size_t)p * SZc;

    int bh = b * Hc + h;
    int r0 = rc * 16;
    int c = threadIdx.x;
    int lane = c & 63, wid = c >> 6;

    __shared__ __align__(16) short sVT[16 * 264];
    __shared__ __align__(16) short sEb[16 * 264];
    __shared__ float sQ[16][16];
    __shared__ float sPart[4 * 280];   // [wid][quad*72 + r*16 + mr]
    __shared__ float sSum[16 * 4];
    __shared__ float sm1w[32], sm1b[16], sm2w[16], sm2bS[1];

    float kreg[16];
    {
        const float* kp = K + ((size_t)bh * Nc + c) * DKc;
        const float* vp = V + ((size_t)bh * Nc + c) * DKc;
#pragma unroll
        for (int i = 0; i < 4; ++i) {
            float4 kv = *(const float4*)(kp + i * 4);
            float4 vv = *(const float4*)(vp + i * 4);
            kreg[i * 4]     = kv.x; kreg[i * 4 + 1] = kv.y;
            kreg[i * 4 + 2] = kv.z; kreg[i * 4 + 3] = kv.w;
            sVT[(i * 4 + 0) * 264 + c] = f2bs(vv.x);
            sVT[(i * 4 + 1) * 264 + c] = f2bs(vv.y);
            sVT[(i * 4 + 2) * 264 + c] = f2bs(vv.z);
            sVT[(i * 4 + 3) * 264 + c] = f2bs(vv.w);
        }
    }
    if (c < 64) {
        float4 qv = *(const float4*)(Q + ((size_t)bh * Nc + r0) * DKc + c * 4);
        int rl = c >> 2, off = (c & 3) * 4;
        sQ[rl][off] = qv.x; sQ[rl][off + 1] = qv.y;
        sQ[rl][off + 2] = qv.z; sQ[rl][off + 3] = qv.w;
    } else if (c < 96)   sm1w[c - 64]  = m1w[h * 32 + (c - 64)];
    else if (c < 112)    sm1b[c - 96]  = m1b[h * 16 + (c - 96)];
    else if (c < 128)    sm2w[c - 112] = m2w[h * 16 + (c - 112)];
    else if (c == 128)   sm2bS[0] = m2b[h];
    __syncthreads();

    // pack MLP coefficients into _Float16x2 registers (one-time per thread)
    h2 pa2[8], pb2[8], pc2[8], pw2[8];
#pragma unroll
    for (int m = 0; m < 8; ++m) {
        pa2[m] = (h2){(_Float16)sm1w[2 * m], (_Float16)sm1w[2 * m + 1]};
        pb2[m] = (h2){(_Float16)sm1w[16 + 2 * m], (_Float16)sm1w[16 + 2 * m + 1]};
        pc2[m] = (h2){(_Float16)sm1b[2 * m], (_Float16)sm1b[2 * m + 1]};
        pw2[m] = (h2){(_Float16)sm2w[2 * m], (_Float16)sm2w[2 * m + 1]};
    }
    const h2 z2 = (h2){(_Float16)0.f, (_Float16)0.f};
    float m2bias = sm2bS[0];

    const float* costR = cost + (size_t)b * Nc * Nc;
    float creg[16];
    if (tr) {
#pragma unroll
        for (int g = 0; g < 4; ++g) {
            float4 cv = *(const float4*)(costR + (size_t)c * Nc + r0 + g * 4);
            creg[g * 4]     = cv.x; creg[g * 4 + 1] = cv.y;
            creg[g * 4 + 2] = cv.z; creg[g * 4 + 3] = cv.w;
        }
    }

    for (int rl = 0; rl < 16; ++rl) {
        float dot = 0.f;
#pragma unroll
        for (int k = 0; k < 16; ++k) dot += kreg[k] * sQ[rl][k];
        dot *= 0.25f;
        float cost_v = tr ? creg[rl] : costR[(size_t)(r0 + rl) * Nc + c];
        _Float16 dh = (_Float16)dot;
        _Float16 ch = (_Float16)cost_v;
        h2 d2 = (h2){dh, dh};
        h2 cv2 = (h2){ch, ch};
        h2 acc2 = z2;
#pragma unroll
        for (int m = 0; m < 8; ++m) {
            h2 t = d2 * pa2[m] + (cv2 * pb2[m] + pc2[m]);
            t = __builtin_elementwise_max(t, z2);
            acc2 += t * pw2[m];
        }
        float mixed = m2bias + (float)acc2.x + (float)acc2.y;
        float e = __expf(mixed);
        sEb[rl * 264 + c] = f2bs(e);
        float s = e;
#pragma unroll
        for (int off = 32; off > 0; off >>= 1) s += __shfl_xor(s, off);
        if (lane == 0) sSum[rl * 4 + wid] = s;
    }
    __syncthreads();

    {
        int mr = lane & 15, quad = lane >> 4;
        const short* pa = &sEb[mr * 264 + wid * 64 + quad * 8];
        const short* pb = &sVT[mr * 264 + wid * 64 + quad * 8];
        f32x4 acc = {0.f, 0.f, 0.f, 0.f};
        bfrag8 a0 = *(const bfrag8*)pa;
        bfrag8 b0 = *(const bfrag8*)pb;
        acc = __builtin_amdgcn_mfma_f32_16x16x32_bf16(a0, b0, acc, 0, 0, 0);
        bfrag8 a1 = *(const bfrag8*)(pa + 32);
        bfrag8 b1 = *(const bfrag8*)(pb + 32);
        acc = __builtin_amdgcn_mfma_f32_16x16x32_bf16(a1, b1, acc, 0, 0, 0);
        // C layout: row = quad*4+r (m index), col = mr (n index)
#pragma unroll
        for (int r = 0; r < 4; ++r)
            sPart[wid * 280 + quad * 72 + r * 16 + mr] = acc[r];
    }
    __syncthreads();

    {
        int r = c >> 4, dk = c & 15;
        int quad = r >> 2, rr = r & 3;
        int idx = quad * 72 + rr * 16 + dk;
        float o = sPart[idx] + sPart[280 + idx] + sPart[560 + idx] + sPart[840 + idx];
        float sum = sSum[r * 4] + sSum[r * 4 + 1] + sSum[r * 4 + 2] + sSum[r * 4 + 3];
        out_concat[((size_t)(b * Nc + r0 + r)) * Dc + h * DKc + dk] =
            __float2bfloat16(o / sum);
    }
}

// ---------------------------------------------------------------------------
// Dispatch 4: concat GEMM + bias + residual + stats1 atomics. grid (32,8,2).
// ---------------------------------------------------------------------------
__global__ void gemm_cat_kernel(const short* __restrict__ attnb, const short* __restrict__ WT,
                                const float* rcb, const float* ccb,
                                const float* __restrict__ resR, const float* __restrict__ resC,
                                float* __restrict__ x1, float* __restrict__ stats1) {
    int p = blockIdx.z;
    const short* A  = attnb + (size_t)p * SZc;
    const short* BT = WT + (size_t)p * WHALF + 196608;
    const float* bias = p ? ccb : rcb;
    const float* res  = p ? resC : resR;
    float* outF = x1 + (size_t)p * SZc;
    float* st   = stats1 + p * 4096;

    int lane = threadIdx.x & 63, w = threadIdx.x >> 6;
    int m_base = blockIdx.x * 64 + (w & 1) * 32;
    int n_base = blockIdx.y * 32 + (w >> 1) * 16;
    int mr = lane & 15, quad = lane >> 4;

    const short* pa0 = A + (size_t)(m_base + mr) * 256 + quad * 8;
    const short* pa1 = pa0 + (size_t)16 * 256;
    const short* pb  = BT + (size_t)(n_base + mr) * 256 + quad * 8;

    f32x4 acc0 = {0.f, 0.f, 0.f, 0.f}, acc1 = {0.f, 0.f, 0.f, 0.f};
    mfma_loop(pa0, pa1, pb, 256, acc0, acc1);

    int col = n_base + mr;
    float bv = bias[col];
    int bb = m_base >> 8;
    float ssum = 0.f, ssq = 0.f;
#pragma unroll
    for (int r = 0; r < 4; ++r) {
        int row0 = m_base + quad * 4 + r;
        int row1 = row0 + 16;
        float v0 = acc0[r] + bv + res[(size_t)row0 * 256 + col];
        float v1 = acc1[r] + bv + res[(size_t)row1 * 256 + col];
        outF[(size_t)row0 * 256 + col] = v0;
        outF[(size_t)row1 * 256 + col] = v1;
        ssum += v0 + v1;
        ssq  += v0 * v0 + v1 * v1;
    }
    atomicAdd(&st[(bb * 256 + col) * 2],     ssum);
    atomicAdd(&st[(bb * 256 + col) * 2 + 1], ssq);
}

// ---------------------------------------------------------------------------
// Dispatch 5: FF1 with on-the-fly norm1 of A. grid (32,16,2).
// ---------------------------------------------------------------------------
__global__ __launch_bounds__(256) void gemm_ff1n_kernel(
        const float* __restrict__ x1, const float* __restrict__ stats1,
        const float* rn1s, const float* rn1b, const float* cn1s, const float* cn1b,
        const short* __restrict__ WT, const float* rb1, const float* cb1,
        bf16* __restrict__ ffh) {
    int p = blockIdx.z;
    const float* X   = x1 + (size_t)p * SZc;
    const float* st  = stats1 + p * 4096;
    const float* n1s = p ? cn1s : rn1s;
    const float* n1b = p ? cn1b : rn1b;
    const short* BT  = WT + (size_t)p * WHALF + 262144;
    const float* bias = p ? cb1 : rb1;
    bf16* outB = ffh + (size_t)p * FFH;

    __shared__ __align__(16) short sA[64 * 264];
    int c = threadIdx.x;
    int m_base = blockIdx.x * 64;
    int b = m_base >> 8;

    float s = st[(b * 256 + c) * 2];
    float q = st[(b * 256 + c) * 2 + 1];
    float mean = s * (1.f / Nc);
    float var = q * (1.f / Nc) - mean * mean;
    float inv = rsqrtf(var + 1e-5f) * n1s[c];
    float nb = n1b[c];
#pragma unroll 8
    for (int i = 0; i < 64; ++i) {
        float v = X[(size_t)(m_base + i) * 256 + c];
        sA[i * 264 + c] = f2bs((v - mean) * inv + nb);
    }
    __syncthreads();

    int lane = c & 63, w = c >> 6;
    int mloc = (w & 1) * 32;
    int n_base = blockIdx.y * 32 + (w >> 1) * 16;
    int mr = lane & 15, quad = lane >> 4;

    const short* pa0 = &sA[(mloc + mr) * 264 + quad * 8];
    const short* pa1 = pa0 + 16 * 264;
    const short* pb  = BT + (size_t)(n_base + mr) * 256 + quad * 8;

    f32x4 acc0 = {0.f, 0.f, 0.f, 0.f}, acc1 = {0.f, 0.f, 0.f, 0.f};
#pragma unroll
    for (int kt = 0; kt < 256; kt += 32) {
        bfrag8 a0 = *(const bfrag8*)(pa0 + kt);
        bfrag8 a1 = *(const bfrag8*)(pa1 + kt);
        bfrag8 bb = *(const bfrag8*)(pb + kt);
        acc0 = __builtin_amdgcn_mfma_f32_16x16x32_bf16(a0, bb, acc0, 0, 0, 0);
        acc1 = __builtin_amdgcn_mfma_f32_16x16x32_bf16(a1, bb, acc1, 0, 0, 0);
    }

    int col = n_base + mr;
    float bv = bias[col];
#pragma unroll
    for (int r = 0; r < 4; ++r) {
        int row0 = m_base + mloc + quad * 4 + r;
        int row1 = row0 + 16;
        outB[(size_t)row0 * 512 + col] = __float2bfloat16(fmaxf(acc0[r] + bv, 0.f));
        outB[(size_t)row1 * 512 + col] = __float2bfloat16(fmaxf(acc1[r] + bv, 0.f));
    }
}

// ---------------------------------------------------------------------------
// Dispatch 6: FF2 + recomputed norm1 residual + stats2 atomics. grid (32,8,2).
// ---------------------------------------------------------------------------
__global__ void gemm_ff2n_kernel(const short* __restrict__ ffh, const short* __restrict__ WT,
                                 const float* rb2, const float* cb2,
                                 const float* __restrict__ x1, const float* __restrict__ stats1,
                                 const float* rn1s, const float* rn1b,
                                 const float* cn1s, const float* cn1b,
                                 float* __restrict__ ff2, float* __restrict__ stats2) {
    int p = blockIdx.z;
    const short* A  = ffh + (size_t)p * FFH;
    const short* BT = WT + (size_t)p * WHALF + 393216;
    const float* bias = p ? cb2 : rb2;
    const float* X   = x1 + (size_t)p * SZc;
    const float* st1 = stats1 + p * 4096;
    const float* n1s = p ? cn1s : rn1s;
    const float* n1b = p ? cn1b : rn1b;
    float* outF = ff2 + (size_t)p * SZc;
    float* st2  = stats2 + p * 4096;

    int lane = threadIdx.x & 63, w = threadIdx.x >> 6;
    int m_base = blockIdx.x * 64 + (w & 1) * 32;
    int n_base = blockIdx.y * 32 + (w >> 1) * 16;
    int mr = lane & 15, quad = lane >> 4;

    const short* pa0 = A + (size_t)(m_base + mr) * 512 + quad * 8;
    const short* pa1 = pa0 + (size_t)16 * 512;
    const short* pb  = BT + (size_t)(n_base + mr) * 512 + quad * 8;

    f32x4 acc0 = {0.f, 0.f, 0.f, 0.f}, acc1 = {0.f, 0.f, 0.f, 0.f};
    mfma_loop(pa0, pa1, pb, 512, acc0, acc1);

    int col = n_base + mr;
    int bb = m_base >> 8;
    float s1 = st1[(bb * 256 + col) * 2];
    float q1 = st1[(bb * 256 + col) * 2 + 1];
    float mean1 = s1 * (1.f / Nc);
    float var1 = q1 * (1.f / Nc) - mean1 * mean1;
    float inv1 = rsqrtf(var1 + 1e-5f) * n1s[col];
    float nb1 = n1b[col];
    float bv = bias[col];

    float ssum = 0.f, ssq = 0.f;
#pragma unroll
    for (int r = 0; r < 4; ++r) {
        int row0 = m_base + quad * 4 + r;
        int row1 = row0 + 16;
        float res0 = (X[(size_t)row0 * 256 + col] - mean1) * inv1 + nb1;
        float res1 = (X[(size_t)row1 * 256 + col] - mean1) * inv1 + nb1;
        float v0 = acc0[r] + bv + res0;
        float v1 = acc1[r] + bv + res1;
        outF[(size_t)row0 * 256 + col] = v0;
        outF[(size_t)row1 * 256 + col] = v1;
        ssum += v0 + v1;
        ssq  += v0 * v0 + v1 * v1;
    }
    atomicAdd(&st2[(bb * 256 + col) * 2],     ssum);
    atomicAdd(&st2[(bb * 256 + col) * 2 + 1], ssq);
}

// ---------------------------------------------------------------------------
// Dispatch 7: final norm2 apply -> output. grid (2048, 2).
// ---------------------------------------------------------------------------
__global__ void apply_kernel(const float* __restrict__ x, const float* __restrict__ stats,
                             const float* sR, const float* bR,
                             const float* sC, const float* bC,
                             float* __restrict__ outF) {
    int p = blockIdx.y;
    int row = blockIdx.x;
    int b = row >> 8;
    int d = threadIdx.x;
    const float* st = stats + p * 4096;
    float sum = st[(b * 256 + d) * 2];
    float sq  = st[(b * 256 + d) * 2 + 1];
    float mean = sum * (1.f / Nc);
    float var = sq * (1.f / Nc) - mean * mean;
    float inv = rsqrtf(var + 1e-5f);
    float scale = (p ? sC : sR)[d];
    float bias  = (p ? bC : bR)[d];
    float v = x[(size_t)p * SZc + (size_t)row * Dc + d];
    outF[(size_t)p * SZc + (size_t)row * Dc + d] = (v - mean) * inv * scale + bias;
}

extern "C" void kernel_launch(void* const* d_in, const int* in_sizes, int n_in,
                              void* d_out, int out_size, void* d_ws, size_t ws_size,
                              hipStream_t stream) {
    const float* row_emb = (const float*)d_in[0];
    const float* col_emb = (const float*)d_in[1];
    const float* cost    = (const float*)d_in[2];
    float* out = (float*)d_out;
    float* ws = (float*)d_ws;
    // per-half param index: 0 Wq, 1 Wk, 2 Wv, 3 m1w, 4 m1b, 5 m2w, 6 m2b,
    // 7 cw, 8 cb, 9 n1s, 10 n1b, 11 w1, 12 b1, 13 w2, 14 b2, 15 n2s, 16 n2b
#define RP(i) ((const float*)d_in[3 + (i)])
#define CP(i) ((const float*)d_in[20 + (i)])

    float* qkv    = ws;                            // 6 SZ
    float* x1     = ws + 6 * (size_t)SZc;          // 2 SZ
    float* ff2    = ws + 8 * (size_t)SZc;          // 2 SZ
    float* statsB = ws + 10 * (size_t)SZc;         // 16384
    bf16* bfbase  = (bf16*)(statsB + 16384);
    bf16* embRb = bfbase;                          // SZ
    bf16* embCb = embRb + SZc;                     // SZ
    bf16* attnb = embCb + SZc;                     // 2 SZ
    bf16* ffh   = attnb + 2 * (size_t)SZc;         // 4 SZ
    bf16* WT    = ffh + 4 * (size_t)SZc;           // 2 SZ
    float* stats1 = statsB;
    float* stats2 = statsB + 8192;

    setup_kernel<<<dim3(256, 15), 256, 0, stream>>>(
        row_emb, col_emb, embRb, embCb, statsB,
        RP(0), RP(1), RP(2), RP(7), RP(11), RP(13),
        CP(0), CP(1), CP(2), CP(7), CP(11), CP(13), WT);
    gemm_qkv_kernel<<<dim3(32, 8, 6), 256, 0, stream>>>(
        (const short*)embRb, (const short*)embCb, (const short*)WT, qkv);
    attn_kernel<<<dim3(Bc, Hc, 32), 256, 0, stream>>>(
        qkv, cost, RP(3), RP(4), RP(5), RP(6), CP(3), CP(4), CP(5), CP(6), attnb);
    gemm_cat_kernel<<<dim3(32, 8, 2), 256, 0, stream>>>(
        (const short*)attnb, (const short*)WT, RP(8), CP(8), row_emb, col_emb, x1, stats1);
    gemm_ff1n_kernel<<<dim3(32, 16, 2), 256, 0, stream>>>(
        x1, stats1, RP(9), RP(10), CP(9), CP(10),
        (const short*)WT, RP(12), CP(12), ffh);
    gemm_ff2n_kernel<<<dim3(32, 8, 2), 256, 0, stream>>>(
        (const short*)ffh, (const short*)WT, RP(14), CP(14),
        x1, stats1, RP(9), RP(10), CP(9), CP(10), ff2, stats2);
    apply_kernel<<<dim3(2048, 2), 256, 0, stream>>>(
        ff2, stats2, RP(15), RP(16), CP(15), CP(16), out);
#undef RP
#undef CP
}